// Round 24
// baseline (177.429 us; speedup 1.0000x reference)
//
#include <hip/hip_runtime.h>
#include <hip/hip_fp16.h>
#include <math.h>

#define D 64
#define EPB 1024  // elements per scan block (256 threads x 4)

typedef _Float16 f16x8 __attribute__((ext_vector_type(8)));
typedef _Float16 f16x4 __attribute__((ext_vector_type(4)));
typedef float f32x4 __attribute__((ext_vector_type(4)));

__device__ __forceinline__ float lrelu(float x) { return fmaxf(x, 0.f) + 0.01f * fminf(x, 0.f); }

// ---------------- count edges per node ----------------
__global__ void k_count(const int* __restrict__ ru, const int* __restrict__ ri,
                        int* __restrict__ cnt_u, int* __restrict__ cnt_i, int R) {
    int r = blockIdx.x * blockDim.x + threadIdx.x;
    if (r >= R) return;
    atomicAdd(&cnt_u[ru[r]], 1);
    atomicAdd(&cnt_i[ri[r]], 1);
}

// ---------------- fill user-CSR edge list: slot -> (u, it) ----------------
__global__ void k_fill_u(const int* __restrict__ ru, const int* __restrict__ ri,
                         int* __restrict__ cur_u, int2* __restrict__ edges, int R) {
    int r = blockIdx.x * blockDim.x + threadIdx.x;
    if (r >= R) return;
    int u = ru[r], it = ri[r];
    int j = atomicAdd(&cur_u[u], 1);
    edges[j] = make_int2(u, it);
}

// ---------------- per-node GEMVs via MFMA -> SoA pack [node][4 fields][64 f16] ----
// Prologue zeroes the cnt+flags region (k_nodes is independent of the CSR chain;
// consumers run in later kernels). X/P tile staged in LDS once per block.
__global__ __launch_bounds__(256) void k_nodes_mfma(
    const float* __restrict__ Xu, const float* __restrict__ Pu, int nu, int ntu,
    const float* __restrict__ Xi_, const float* __restrict__ Pi, int ni, int nti,
    const float* __restrict__ Wsrc, const float* __restrict__ bsrc,
    const float* __restrict__ Wdst, const float* __restrict__ bdst,
    const float* __restrict__ Wo,   const float* __restrict__ bo,
    const float* __restrict__ Wu,   const float* __restrict__ bu,
    __half* __restrict__ packU, __half* __restrict__ Xuh,
    __half* __restrict__ packI, __half* __restrict__ Xih,
    int* __restrict__ zero_region, int nzero) {
    __shared__ float sX[16 * 68];      // +4 pad: <=2-way bank aliasing (free)
    __shared__ float sP[16 * 68];
    __shared__ __half sD[4][16][72];   // +8 pad
    __shared__ float sb[4][64];
    int tid = threadIdx.x;
    int lane = tid & 63, w = tid >> 6;
    int col = lane & 15, kg = lane >> 4;

    // zero cnt_u|cnt_i|flags for the CSR chain (later kernels consume)
    for (int j = blockIdx.x * 256 + tid; j < nzero; j += gridDim.x * 256)
        zero_region[j] = 0;

    {
        int c = tid & 63, m = tid >> 6;
        const float* bp = (m == 0) ? bsrc : (m == 1) ? bdst : (m == 2) ? bo : bu;
        sb[m][c] = bp[c];
    }
    const float* W = (w == 0) ? Wsrc : (w == 1) ? Wdst : (w == 2) ? Wo : Wu;
    f16x8 Bf[2][4];
#pragma unroll
    for (int kt = 0; kt < 2; ++kt)
#pragma unroll
        for (int ct = 0; ct < 4; ++ct) {
            int c = ct * 16 + col;
            int k0 = kt * 32 + kg * 8;
            f16x8 bfrag;
#pragma unroll
            for (int j = 0; j < 8; ++j) bfrag[j] = (_Float16)W[(k0 + j) * 64 + c];
            Bf[kt][ct] = bfrag;
        }
    __syncthreads();

    int T = ntu + nti;
    for (int tile = blockIdx.x; tile < T; tile += gridDim.x) {
        bool usr = tile < ntu;
        const float* X = usr ? Xu : Xi_;
        const float* P = usr ? Pu : Pi;
        __half* pack = usr ? packU : packI;
        __half* Xh = usr ? Xuh : Xih;
        int n = usr ? nu : ni;
        int nb = (usr ? tile : tile - ntu) * 16;

        // stage 16 rows of X and P (one float4 per thread per array)
        {
            int rl = tid >> 4;            // 0..15
            int c0s = (tid & 15) * 4;     // 0..60
            int grow = nb + rl; if (grow >= n) grow = n - 1;
            *(float4*)&sX[rl * 68 + c0s] = *(const float4*)(X + (size_t)grow * 64 + c0s);
            *(float4*)&sP[rl * 68 + c0s] = *(const float4*)(P + (size_t)grow * 64 + c0s);
        }
        __syncthreads();
        // A fragments from LDS
        const float* srow = (w == 3) ? &sP[col * 68] : &sX[col * 68];
        float4 a0 = *(const float4*)(srow + kg * 8);
        float4 a1 = *(const float4*)(srow + kg * 8 + 4);
        float4 a2 = *(const float4*)(srow + 32 + kg * 8);
        float4 a3 = *(const float4*)(srow + 32 + kg * 8 + 4);
        f16x8 A0, A1;
        A0[0] = (_Float16)a0.x; A0[1] = (_Float16)a0.y; A0[2] = (_Float16)a0.z; A0[3] = (_Float16)a0.w;
        A0[4] = (_Float16)a1.x; A0[5] = (_Float16)a1.y; A0[6] = (_Float16)a1.z; A0[7] = (_Float16)a1.w;
        A1[0] = (_Float16)a2.x; A1[1] = (_Float16)a2.y; A1[2] = (_Float16)a2.z; A1[3] = (_Float16)a2.w;
        A1[4] = (_Float16)a3.x; A1[5] = (_Float16)a3.y; A1[6] = (_Float16)a3.z; A1[7] = (_Float16)a3.w;
        if (w == 0) {   // fp16 X copy for k_agg (dup tail writes benign)
            int arow = nb + col; if (arow >= n) arow = n - 1;
            *(f16x8*)(Xh + (size_t)arow * 64 + kg * 8) = A0;
            *(f16x8*)(Xh + (size_t)arow * 64 + 32 + kg * 8) = A1;
        }
        f32x4 acc[4];
#pragma unroll
        for (int ct = 0; ct < 4; ++ct) {
            acc[ct] = (f32x4){0.f, 0.f, 0.f, 0.f};
            acc[ct] = __builtin_amdgcn_mfma_f32_16x16x32_f16(A0, Bf[0][ct], acc[ct], 0, 0, 0);
            acc[ct] = __builtin_amdgcn_mfma_f32_16x16x32_f16(A1, Bf[1][ct], acc[ct], 0, 0, 0);
        }
        __syncthreads();   // previous tile's assembly done
#pragma unroll
        for (int ct = 0; ct < 4; ++ct)
#pragma unroll
            for (int jj = 0; jj < 4; ++jj)
                sD[w][kg * 4 + jj][ct * 16 + col] = __float2half(acc[ct][jj]);
        __syncthreads();
        // assembly: thread handles node r = tid>>4, 4 features c0..c0+3, all 4 fields
        int r = tid >> 4, c0 = (tid & 15) * 4;
        int node = nb + r;
        if (node < n) {
            __half* dst = pack + (size_t)node * 256;
            f16x4 v[4];
#pragma unroll
            for (int q = 0; q < 4; ++q) {
                int c = c0 + q;
                float hs = __half2float(sD[0][r][c]) + sb[0][c];
                float hds = 0.5f * (__half2float(sD[1][r][c]) + sb[1][c]);
                float ho = __half2float(sD[2][r][c]) + sb[2][c];
                float pw = __half2float(sD[3][r][c]) + sb[3][c];
                v[0][q] = (_Float16)(hs + hds);
                v[1][q] = (_Float16)hds;
                v[2][q] = (_Float16)ho;
                v[3][q] = (_Float16)pw;
            }
#pragma unroll
            for (int m = 0; m < 4; ++m)
                *(f16x4*)(dst + m * 64 + c0) = v[m];
        }
    }
}

// ---------------- single-pass scan with decoupled lookback (both sides) -------
// 74 co-resident blocks; flags zeroed by k_nodes prologue. Deterministic.
__global__ __launch_bounds__(256) void k_scan1(
    const int* __restrict__ cnt_u, int* __restrict__ off_u, int* __restrict__ cur_u, int nu,
    const int* __restrict__ cnt_i, int* __restrict__ off_i, int* __restrict__ cur_i, int ni,
    int* __restrict__ bsum, int* __restrict__ flags, int Bu, int Bi) {
    int b = blockIdx.x;
    const int* cnt; int* off; int* cur; int n; int lb; int sb_; int B;
    if (b < Bu) { cnt = cnt_u; off = off_u; cur = cur_u; n = nu; lb = b; sb_ = 0;  B = Bu; }
    else        { cnt = cnt_i; off = off_i; cur = cur_i; n = ni; lb = b - Bu; sb_ = Bu; B = Bi; }
    int t = threadIdx.x;
    int idx0 = lb * EPB + t * 4;
    int v[4];
#pragma unroll
    for (int k = 0; k < 4; ++k) v[k] = (idx0 + k < n) ? cnt[idx0 + k] : 0;
    int s = v[0] + v[1] + v[2] + v[3];
    int lane = t & 63, w = t >> 6;
    int x = s;
#pragma unroll
    for (int o = 1; o < 64; o <<= 1) {
        int y = __shfl_up(x, o, 64);
        if (lane >= o) x += y;
    }
    __shared__ int wsum[4];
    __shared__ int sboff;
    if (lane == 63) wsum[w] = x;
    __syncthreads();
    int woff = 0;
    for (int j = 0; j < w; ++j) woff += wsum[j];
    int run = woff + x - s;      // exclusive prefix for this thread
    int tot = wsum[0] + wsum[1] + wsum[2] + wsum[3];
    // publish own total, then look back over predecessors of this side
    if (t == 0) {
        bsum[b] = tot;
        __threadfence();
        __hip_atomic_store(&flags[b], 1, __ATOMIC_RELEASE, __HIP_MEMORY_SCOPE_AGENT);
        int boff = 0;
        for (int j = sb_; j < b; ++j) {
            while (__hip_atomic_load(&flags[j], __ATOMIC_ACQUIRE,
                                     __HIP_MEMORY_SCOPE_AGENT) == 0) { }
            boff += bsum[j];
        }
        sboff = boff;
    }
    __syncthreads();
    int boff = sboff;
#pragma unroll
    for (int k = 0; k < 4; ++k) {
        int idx = idx0 + k;
        if (idx < n) {
            int vv = run + boff;
            off[idx] = vv;
            cur[idx] = vv;
        }
        run += v[k];
    }
    if (lb == B - 1 && t == 0) off[n] = boff + tot;   // side total
}

// ---------------- pass 1: user-CSR order, 8 reviews/wave, SoA f16x8 loads ------
__global__ __launch_bounds__(256, 1) void k_rev1(
    const int2* __restrict__ edges,
    const __half* __restrict__ packU, const __half* __restrict__ packI,
    const float4* __restrict__ watt_rep4,
    const float4* __restrict__ watt_agg4, const float* __restrict__ batt_agg,
    int* __restrict__ cur_i,
    float4* __restrict__ pay_su, float4* __restrict__ pay_si,
    int R) {
    int tid = threadIdx.x;
    int lane = tid & 63;
    int f = lane & 7;             // feature block: features 8f..8f+7
    int j = blockIdx.x * 32 + (tid >> 6) * 8 + (lane >> 3);
    if (j >= R) return;
    int2 e = edges[j];
    const __half* pu = packU + (size_t)e.x * 256 + f * 8;
    const __half* pi = packI + (size_t)e.y * 256 + f * 8;
    f16x8 f0u = *(const f16x8*)(pu);
    f16x8 hdu = *(const f16x8*)(pu + 64);
    f16x8 hou = *(const f16x8*)(pu + 128);
    f16x8 pwu = *(const f16x8*)(pu + 192);
    f16x8 f0i = *(const f16x8*)(pi);
    f16x8 hdi = *(const f16x8*)(pi + 64);
    f16x8 hoi = *(const f16x8*)(pi + 128);
    f16x8 pwi = *(const f16x8*)(pi + 192);

    // stage 1: lrelu(f0 + hd_other) . watt_rep
    f16x8 xu = f0u + hdi;
    f16x8 xi = f0i + hdu;
    float4 wrA = watt_rep4[f * 2], wrB = watt_rep4[f * 2 + 1];
    float tu =
        lrelu((float)xu[0]) * wrA.x + lrelu((float)xu[1]) * wrA.y +
        lrelu((float)xu[2]) * wrA.z + lrelu((float)xu[3]) * wrA.w +
        lrelu((float)xu[4]) * wrB.x + lrelu((float)xu[5]) * wrB.y +
        lrelu((float)xu[6]) * wrB.z + lrelu((float)xu[7]) * wrB.w;
    float ti =
        lrelu((float)xi[0]) * wrA.x + lrelu((float)xi[1]) * wrA.y +
        lrelu((float)xi[2]) * wrA.z + lrelu((float)xi[3]) * wrA.w +
        lrelu((float)xi[4]) * wrB.x + lrelu((float)xi[5]) * wrB.y +
        lrelu((float)xi[6]) * wrB.z + lrelu((float)xi[7]) * wrB.w;
#pragma unroll
    for (int o = 4; o; o >>= 1) {
        tu += __shfl_xor(tu, o, 64);
        ti += __shfl_xor(ti, o, 64);
    }
    // wu = sigmoid(tu - ti); batt_rep cancels
    float wu = 1.f / (1.f + __expf(ti - tu));
    float wi = 1.f - wu;
    // stage 2: ho = wu*hou + wi*hoi; logits vs watt_agg
    float4 waA = watt_agg4[f * 2], waB = watt_agg4[f * 2 + 1];
    float zu = 0.f, zi = 0.f;
#pragma unroll
    for (int k = 0; k < 8; ++k) {
        float ho = wu * (float)hou[k] + wi * (float)hoi[k];
        float wa = (k < 4) ? ((const float*)&waA)[k] : ((const float*)&waB)[k - 4];
        zu += lrelu(ho + (float)pwi[k]) * wa;
        zi += lrelu(ho + (float)pwu[k]) * wa;
    }
#pragma unroll
    for (int o = 4; o; o >>= 1) {
        zu += __shfl_xor(zu, o, 64);
        zi += __shfl_xor(zi, o, 64);
    }
    if (f == 0) {
        float ba = batt_agg[0];
        pay_su[j] = make_float4(zu + ba, wu, __int_as_float(e.y), 0.f);   // sequential
        int j2 = atomicAdd(&cur_i[e.y], 1);
        pay_si[j2] = make_float4(zi + ba, wu, __int_as_float(e.x), 0.f);
    }
}

// ---------------- aggregation: one wave/node; 8-lane groups; no max pass ----
__global__ __launch_bounds__(256, 1) void k_agg(
    const int* __restrict__ off_u, const int* __restrict__ off_i,
    const float4* __restrict__ pay_su, const float4* __restrict__ pay_si,
    const float* __restrict__ Xu, const float* __restrict__ Xi,
    const __half* __restrict__ Xuh, const __half* __restrict__ Xih,
    float* __restrict__ out, int nu, int ntot) {
    int tid = threadIdx.x;
    int lane = tid & 63;
    int idx = blockIdx.x * 4 + (tid >> 6);
    if (idx >= ntot) return;
    bool user = idx < nu;
    int d = user ? idx : idx - nu;
    const int*    offp = user ? off_u : off_i;
    const float4* pay  = user ? pay_su : pay_si;
    const float*  Xown = user ? Xu : Xi;
    const __half* Xoth = user ? Xih : Xuh;
    int s = offp[d], e = offp[d + 1];
    if (s == e) { out[(size_t)idx * D + lane] = 0.f; return; }
    int g = lane >> 3;       // edge group 0..7
    int l = lane & 7;        // feature sub-lane: features 8l..8l+7
    float msum = 0.f, mcoef = 0.f;
    float acc[8] = {0.f, 0.f, 0.f, 0.f, 0.f, 0.f, 0.f, 0.f};
    for (int j = s + g; j < e; j += 8) {
        float4 p = pay[j];                         // broadcast within group
        float ex = __expf(p.x);
        float wown = user ? p.y : 1.f - p.y;
        msum += ex;
        mcoef += ex * wown;
        float cv = ex * (1.f - wown);
        int o2 = __float_as_int(p.z);
        const __half2* row = (const __half2*)(Xoth + (size_t)o2 * D + 8 * l);
        float2 f0 = __half22float2(row[0]);
        float2 f1 = __half22float2(row[1]);
        float2 f2 = __half22float2(row[2]);
        float2 f3 = __half22float2(row[3]);
        acc[0] += cv * f0.x; acc[1] += cv * f0.y;
        acc[2] += cv * f1.x; acc[3] += cv * f1.y;
        acc[4] += cv * f2.x; acc[5] += cv * f2.y;
        acc[6] += cv * f3.x; acc[7] += cv * f3.y;
    }
#pragma unroll
    for (int o = 32; o >= 8; o >>= 1) {
        msum  += __shfl_xor(msum, o, 64);
        mcoef += __shfl_xor(mcoef, o, 64);
#pragma unroll
        for (int q = 0; q < 8; ++q) acc[q] += __shfl_xor(acc[q], o, 64);
    }
    if (g == 0) {
        float inv = 1.f / msum;
        const float4* xo = (const float4*)(Xown + (size_t)d * D + 8 * l);
        float4 x0 = xo[0], x1 = xo[1];
        float4 r0, r1;
        r0.x = (mcoef * x0.x + acc[0]) * inv;
        r0.y = (mcoef * x0.y + acc[1]) * inv;
        r0.z = (mcoef * x0.z + acc[2]) * inv;
        r0.w = (mcoef * x0.w + acc[3]) * inv;
        r1.x = (mcoef * x1.x + acc[4]) * inv;
        r1.y = (mcoef * x1.y + acc[5]) * inv;
        r1.z = (mcoef * x1.z + acc[6]) * inv;
        r1.w = (mcoef * x1.w + acc[7]) * inv;
        float4* op = (float4*)(out + (size_t)idx * D + 8 * l);
        op[0] = r0;
        op[1] = r1;
    }
}

extern "C" void kernel_launch(void* const* d_in, const int* in_sizes, int n_in,
                              void* d_out, int out_size, void* d_ws, size_t ws_size,
                              hipStream_t stream) {
    const float* Xu        = (const float*)d_in[0];
    const float* Xi        = (const float*)d_in[1];
    const float* Wsrc      = (const float*)d_in[2];
    const float* bsrc      = (const float*)d_in[3];
    const float* Wdst      = (const float*)d_in[4];
    const float* bdst      = (const float*)d_in[5];
    const float* watt_rep  = (const float*)d_in[6];
    const float* batt_rep  = (const float*)d_in[7];  (void)batt_rep; // cancels in sigmoid
    const float* Wo        = (const float*)d_in[8];
    const float* bo        = (const float*)d_in[9];
    const float* Wu        = (const float*)d_in[10];
    const float* bu        = (const float*)d_in[11];
    const float* watt_agg  = (const float*)d_in[12];
    const float* batt_agg  = (const float*)d_in[13];
    const float* pref_user = (const float*)d_in[14];
    const float* pref_item = (const float*)d_in[15];
    const int* r_user      = (const int*)d_in[16];
    const int* r_item      = (const int*)d_in[17];

    int nu = in_sizes[0] / D;
    int ni = in_sizes[1] / D;
    int R  = in_sizes[16];

    float* ws = (float*)d_ws;
    size_t off = 0;
    __half* packU = (__half*)(ws + off); off += (size_t)nu * D * 2;   // SoA
    __half* packI = (__half*)(ws + off); off += (size_t)ni * D * 2;
    __half* Xuh = (__half*)(ws + off); off += (size_t)nu * D / 2;
    __half* Xih = (__half*)(ws + off); off += (size_t)ni * D / 2;
    float4* pay_su = (float4*)(ws + off); off += (size_t)R * 4;
    float4* pay_si = (float4*)(ws + off); off += (size_t)R * 4;
    int2* edges = (int2*)(ws + off); off += (size_t)R * 2;
    int* cnt_u = (int*)(ws + off); off += (size_t)nu;         // doubles as cursor
    int* cnt_i = (int*)(ws + off); off += (size_t)ni;
    int* flags = (int*)(ws + off); off += 128;                // lookback flags
    int* bsum  = (int*)(ws + off); off += 128;
    int* off_u = (int*)(ws + off); off += (size_t)nu + 1;
    int* off_i = (int*)(ws + off); off += (size_t)ni + 1;

    // node-level precompute via MFMA (LDS-staged X/P tile); prologue zeroes
    // cnt_u|cnt_i|flags for the CSR chain (no dependency on CSR kernels).
    int nzero = nu + ni + 128;
    int ntu = (nu + 15) / 16, nti = (ni + 15) / 16;
    k_nodes_mfma<<<1024, 256, 0, stream>>>(
        Xu, pref_user, nu, ntu, Xi, pref_item, ni, nti,
        Wsrc, bsrc, Wdst, bdst, Wo, bo, Wu, bu,
        packU, Xuh, packI, Xih, cnt_u, nzero);

    // edge counts
    k_count<<<(R + 255) / 256, 256, 0, stream>>>(r_user, r_item, cnt_u, cnt_i, R);

    // single-pass scan with decoupled lookback (74 co-resident blocks)
    int Bu = (nu + EPB - 1) / EPB, Bi = (ni + EPB - 1) / EPB;
    k_scan1<<<Bu + Bi, 256, 0, stream>>>(
        cnt_u, off_u, cnt_u, nu, cnt_i, off_i, cnt_i, ni, bsum, flags, Bu, Bi);

    // user-CSR edge list
    k_fill_u<<<(R + 255) / 256, 256, 0, stream>>>(r_user, r_item, cnt_u, edges, R);

    // per-review attention in user-CSR order (8 reviews/wave, SoA loads)
    k_rev1<<<(R + 31) / 32, 256, 0, stream>>>(
        edges, packU, packI,
        (const float4*)watt_rep, (const float4*)watt_agg, batt_agg,
        cnt_i, pay_su, pay_si, R);

    // per-destination softmax + weighted sum (no max pass; 8 edges in flight)
    int ntot = nu + ni;
    k_agg<<<(ntot + 3) / 4, 256, 0, stream>>>(
        off_u, off_i, pay_su, pay_si,
        Xu, Xi, Xuh, Xih, (float*)d_out, nu, ntot);
}

// Round 25
// 164.494 us; speedup vs baseline: 1.0786x; 1.0786x over previous
//
#include <hip/hip_runtime.h>
#include <hip/hip_fp16.h>
#include <math.h>

#define D 64
#define EPB 1024  // elements per scan block (256 threads x 4)

typedef _Float16 f16x8 __attribute__((ext_vector_type(8)));
typedef _Float16 f16x4 __attribute__((ext_vector_type(4)));
typedef float f32x4 __attribute__((ext_vector_type(4)));

__device__ __forceinline__ float lrelu(float x) { return fmaxf(x, 0.f) + 0.01f * fminf(x, 0.f); }

// ---------------- init: zero edge counters (vectorized, grid-stride) ----------
__global__ void k_init(int4* __restrict__ p, int n4) {
    int i = blockIdx.x * blockDim.x + threadIdx.x;
    int stride = gridDim.x * blockDim.x;
    int4 z = make_int4(0, 0, 0, 0);
    for (int j = i; j < n4; j += stride) p[j] = z;
}

// ---------------- count edges per node ----------------
__global__ void k_count(const int* __restrict__ ru, const int* __restrict__ ri,
                        int* __restrict__ cnt_u, int* __restrict__ cnt_i, int R) {
    int r = blockIdx.x * blockDim.x + threadIdx.x;
    if (r >= R) return;
    atomicAdd(&cnt_u[ru[r]], 1);
    atomicAdd(&cnt_i[ri[r]], 1);
}

// ---------------- fill user-CSR edge list: slot -> (u, it) ----------------
__global__ void k_fill_u(const int* __restrict__ ru, const int* __restrict__ ri,
                         int* __restrict__ cur_u, int2* __restrict__ edges, int R) {
    int r = blockIdx.x * blockDim.x + threadIdx.x;
    if (r >= R) return;
    int u = ru[r], it = ri[r];
    int j = atomicAdd(&cur_u[u], 1);
    edges[j] = make_int2(u, it);
}

// ---------------- per-node GEMVs via MFMA -> SoA pack [node][4 fields][64 f16] ----
// X/P tile staged in LDS once per block (avoids 3x redundant X reads by waves 0-2).
__global__ __launch_bounds__(256) void k_nodes_mfma(
    const float* __restrict__ Xu, const float* __restrict__ Pu, int nu, int ntu,
    const float* __restrict__ Xi_, const float* __restrict__ Pi, int ni, int nti,
    const float* __restrict__ Wsrc, const float* __restrict__ bsrc,
    const float* __restrict__ Wdst, const float* __restrict__ bdst,
    const float* __restrict__ Wo,   const float* __restrict__ bo,
    const float* __restrict__ Wu,   const float* __restrict__ bu,
    __half* __restrict__ packU, __half* __restrict__ Xuh,
    __half* __restrict__ packI, __half* __restrict__ Xih) {
    __shared__ float sX[16 * 68];      // +4 pad: <=2-way bank aliasing (free)
    __shared__ float sP[16 * 68];
    __shared__ __half sD[4][16][72];   // +8 pad
    __shared__ float sb[4][64];
    int tid = threadIdx.x;
    int lane = tid & 63, w = tid >> 6;
    int col = lane & 15, kg = lane >> 4;

    {
        int c = tid & 63, m = tid >> 6;
        const float* bp = (m == 0) ? bsrc : (m == 1) ? bdst : (m == 2) ? bo : bu;
        sb[m][c] = bp[c];
    }
    const float* W = (w == 0) ? Wsrc : (w == 1) ? Wdst : (w == 2) ? Wo : Wu;
    f16x8 Bf[2][4];
#pragma unroll
    for (int kt = 0; kt < 2; ++kt)
#pragma unroll
        for (int ct = 0; ct < 4; ++ct) {
            int c = ct * 16 + col;
            int k0 = kt * 32 + kg * 8;
            f16x8 bfrag;
#pragma unroll
            for (int j = 0; j < 8; ++j) bfrag[j] = (_Float16)W[(k0 + j) * 64 + c];
            Bf[kt][ct] = bfrag;
        }
    __syncthreads();

    int T = ntu + nti;
    for (int tile = blockIdx.x; tile < T; tile += gridDim.x) {
        bool usr = tile < ntu;
        const float* X = usr ? Xu : Xi_;
        const float* P = usr ? Pu : Pi;
        __half* pack = usr ? packU : packI;
        __half* Xh = usr ? Xuh : Xih;
        int n = usr ? nu : ni;
        int nb = (usr ? tile : tile - ntu) * 16;

        // stage 16 rows of X and P (one float4 per thread per array)
        {
            int rl = tid >> 4;            // 0..15
            int c0s = (tid & 15) * 4;     // 0..60
            int grow = nb + rl; if (grow >= n) grow = n - 1;
            *(float4*)&sX[rl * 68 + c0s] = *(const float4*)(X + (size_t)grow * 64 + c0s);
            *(float4*)&sP[rl * 68 + c0s] = *(const float4*)(P + (size_t)grow * 64 + c0s);
        }
        __syncthreads();
        // A fragments from LDS
        const float* srow = (w == 3) ? &sP[col * 68] : &sX[col * 68];
        float4 a0 = *(const float4*)(srow + kg * 8);
        float4 a1 = *(const float4*)(srow + kg * 8 + 4);
        float4 a2 = *(const float4*)(srow + 32 + kg * 8);
        float4 a3 = *(const float4*)(srow + 32 + kg * 8 + 4);
        f16x8 A0, A1;
        A0[0] = (_Float16)a0.x; A0[1] = (_Float16)a0.y; A0[2] = (_Float16)a0.z; A0[3] = (_Float16)a0.w;
        A0[4] = (_Float16)a1.x; A0[5] = (_Float16)a1.y; A0[6] = (_Float16)a1.z; A0[7] = (_Float16)a1.w;
        A1[0] = (_Float16)a2.x; A1[1] = (_Float16)a2.y; A1[2] = (_Float16)a2.z; A1[3] = (_Float16)a2.w;
        A1[4] = (_Float16)a3.x; A1[5] = (_Float16)a3.y; A1[6] = (_Float16)a3.z; A1[7] = (_Float16)a3.w;
        if (w == 0) {   // fp16 X copy for k_agg (dup tail writes benign)
            int arow = nb + col; if (arow >= n) arow = n - 1;
            *(f16x8*)(Xh + (size_t)arow * 64 + kg * 8) = A0;
            *(f16x8*)(Xh + (size_t)arow * 64 + 32 + kg * 8) = A1;
        }
        f32x4 acc[4];
#pragma unroll
        for (int ct = 0; ct < 4; ++ct) {
            acc[ct] = (f32x4){0.f, 0.f, 0.f, 0.f};
            acc[ct] = __builtin_amdgcn_mfma_f32_16x16x32_f16(A0, Bf[0][ct], acc[ct], 0, 0, 0);
            acc[ct] = __builtin_amdgcn_mfma_f32_16x16x32_f16(A1, Bf[1][ct], acc[ct], 0, 0, 0);
        }
        __syncthreads();   // previous tile's assembly done
#pragma unroll
        for (int ct = 0; ct < 4; ++ct)
#pragma unroll
            for (int jj = 0; jj < 4; ++jj)
                sD[w][kg * 4 + jj][ct * 16 + col] = __float2half(acc[ct][jj]);
        __syncthreads();
        // assembly: thread handles node r = tid>>4, 4 features c0..c0+3, all 4 fields
        int r = tid >> 4, c0 = (tid & 15) * 4;
        int node = nb + r;
        if (node < n) {
            __half* dst = pack + (size_t)node * 256;
            f16x4 v[4];
#pragma unroll
            for (int q = 0; q < 4; ++q) {
                int c = c0 + q;
                float hs = __half2float(sD[0][r][c]) + sb[0][c];
                float hds = 0.5f * (__half2float(sD[1][r][c]) + sb[1][c]);
                float ho = __half2float(sD[2][r][c]) + sb[2][c];
                float pw = __half2float(sD[3][r][c]) + sb[3][c];
                v[0][q] = (_Float16)(hs + hds);
                v[1][q] = (_Float16)hds;
                v[2][q] = (_Float16)ho;
                v[3][q] = (_Float16)pw;
            }
#pragma unroll
            for (int m = 0; m < 4; ++m)
                *(f16x4*)(dst + m * 64 + c0) = v[m];
        }
    }
}

// ---------------- pass 1: user-CSR order, 8 reviews/wave, SoA f16x8 loads ------
__global__ __launch_bounds__(256, 1) void k_rev1(
    const int2* __restrict__ edges,
    const __half* __restrict__ packU, const __half* __restrict__ packI,
    const float4* __restrict__ watt_rep4,
    const float4* __restrict__ watt_agg4, const float* __restrict__ batt_agg,
    int* __restrict__ cur_i,
    float4* __restrict__ pay_su, float4* __restrict__ pay_si,
    int R) {
    int tid = threadIdx.x;
    int lane = tid & 63;
    int f = lane & 7;             // feature block: features 8f..8f+7
    int j = blockIdx.x * 32 + (tid >> 6) * 8 + (lane >> 3);
    if (j >= R) return;
    int2 e = edges[j];
    const __half* pu = packU + (size_t)e.x * 256 + f * 8;
    const __half* pi = packI + (size_t)e.y * 256 + f * 8;
    f16x8 f0u = *(const f16x8*)(pu);
    f16x8 hdu = *(const f16x8*)(pu + 64);
    f16x8 hou = *(const f16x8*)(pu + 128);
    f16x8 pwu = *(const f16x8*)(pu + 192);
    f16x8 f0i = *(const f16x8*)(pi);
    f16x8 hdi = *(const f16x8*)(pi + 64);
    f16x8 hoi = *(const f16x8*)(pi + 128);
    f16x8 pwi = *(const f16x8*)(pi + 192);

    // stage 1: lrelu(f0 + hd_other) . watt_rep
    f16x8 xu = f0u + hdi;
    f16x8 xi = f0i + hdu;
    float4 wrA = watt_rep4[f * 2], wrB = watt_rep4[f * 2 + 1];
    float tu =
        lrelu((float)xu[0]) * wrA.x + lrelu((float)xu[1]) * wrA.y +
        lrelu((float)xu[2]) * wrA.z + lrelu((float)xu[3]) * wrA.w +
        lrelu((float)xu[4]) * wrB.x + lrelu((float)xu[5]) * wrB.y +
        lrelu((float)xu[6]) * wrB.z + lrelu((float)xu[7]) * wrB.w;
    float ti =
        lrelu((float)xi[0]) * wrA.x + lrelu((float)xi[1]) * wrA.y +
        lrelu((float)xi[2]) * wrA.z + lrelu((float)xi[3]) * wrA.w +
        lrelu((float)xi[4]) * wrB.x + lrelu((float)xi[5]) * wrB.y +
        lrelu((float)xi[6]) * wrB.z + lrelu((float)xi[7]) * wrB.w;
#pragma unroll
    for (int o = 4; o; o >>= 1) {
        tu += __shfl_xor(tu, o, 64);
        ti += __shfl_xor(ti, o, 64);
    }
    // wu = sigmoid(tu - ti); batt_rep cancels
    float wu = 1.f / (1.f + __expf(ti - tu));
    float wi = 1.f - wu;
    // stage 2: ho = wu*hou + wi*hoi; logits vs watt_agg
    float4 waA = watt_agg4[f * 2], waB = watt_agg4[f * 2 + 1];
    float zu = 0.f, zi = 0.f;
#pragma unroll
    for (int k = 0; k < 8; ++k) {
        float ho = wu * (float)hou[k] + wi * (float)hoi[k];
        float wa = (k < 4) ? ((const float*)&waA)[k] : ((const float*)&waB)[k - 4];
        zu += lrelu(ho + (float)pwi[k]) * wa;
        zi += lrelu(ho + (float)pwu[k]) * wa;
    }
#pragma unroll
    for (int o = 4; o; o >>= 1) {
        zu += __shfl_xor(zu, o, 64);
        zi += __shfl_xor(zi, o, 64);
    }
    if (f == 0) {
        float ba = batt_agg[0];
        pay_su[j] = make_float4(zu + ba, wu, __int_as_float(e.y), 0.f);   // sequential
        int j2 = atomicAdd(&cur_i[e.y], 1);
        pay_si[j2] = make_float4(zi + ba, wu, __int_as_float(e.x), 0.f);
    }
}

// ---------------- two-level scan: (a) local 1024-elem scans ----------------
__global__ __launch_bounds__(256) void k_scan_local(
    const int* __restrict__ cnt_u, int* __restrict__ off_u, int nu,
    const int* __restrict__ cnt_i, int* __restrict__ off_i, int ni,
    int* __restrict__ bsum, int Bu) {
    int b = blockIdx.x;
    const int* cnt; int* off; int n; int lb;
    if (b < Bu) { cnt = cnt_u; off = off_u; n = nu; lb = b; }
    else        { cnt = cnt_i; off = off_i; n = ni; lb = b - Bu; }
    int t = threadIdx.x;
    int idx0 = lb * EPB + t * 4;
    int v[4];
#pragma unroll
    for (int k = 0; k < 4; ++k) v[k] = (idx0 + k < n) ? cnt[idx0 + k] : 0;
    int s = v[0] + v[1] + v[2] + v[3];
    int lane = t & 63, w = t >> 6;
    int x = s;
#pragma unroll
    for (int o = 1; o < 64; o <<= 1) {
        int y = __shfl_up(x, o, 64);
        if (lane >= o) x += y;
    }
    __shared__ int wsum[4];
    if (lane == 63) wsum[w] = x;
    __syncthreads();
    int woff = 0;
    for (int j = 0; j < w; ++j) woff += wsum[j];
    int run = woff + x - s;      // exclusive prefix for this thread
#pragma unroll
    for (int k = 0; k < 4; ++k) {
        if (idx0 + k < n) off[idx0 + k] = run;
        run += v[k];
    }
    if (t == 255) bsum[b] = woff + x;   // block total
}

// ---------------- (b) add block offsets (inline bsum prefix), init cursors,
//                   write side totals ----------------
__global__ __launch_bounds__(256) void k_scan_add(
    int* __restrict__ off_u, int* __restrict__ cur_u, int nu,
    int* __restrict__ off_i, int* __restrict__ cur_i, int ni,
    const int* __restrict__ bsum, int Bu, int Bi) {
    int b = blockIdx.x;
    int* off; int* cur; int n; int lb; const int* bs; int B;
    if (b < Bu) { off = off_u; cur = cur_u; n = nu; lb = b; bs = bsum; B = Bu; }
    else        { off = off_i; cur = cur_i; n = ni; lb = b - Bu; bs = bsum + Bu; B = Bi; }
    int boff = 0;
    for (int j = 0; j < lb; ++j) boff += bs[j];
    int idx0 = lb * EPB + threadIdx.x * 4;
#pragma unroll
    for (int k = 0; k < 4; ++k) {
        int idx = idx0 + k;
        if (idx < n) {
            int vv = off[idx] + boff;
            off[idx] = vv;
            cur[idx] = vv;
        }
    }
    if (lb == B - 1 && threadIdx.x == 0) off[n] = boff + bs[lb];  // side total
}

// ---------------- aggregation: one wave/node; 8-lane groups; no max pass ----
__global__ __launch_bounds__(256, 1) void k_agg(
    const int* __restrict__ off_u, const int* __restrict__ off_i,
    const float4* __restrict__ pay_su, const float4* __restrict__ pay_si,
    const float* __restrict__ Xu, const float* __restrict__ Xi,
    const __half* __restrict__ Xuh, const __half* __restrict__ Xih,
    float* __restrict__ out, int nu, int ntot) {
    int tid = threadIdx.x;
    int lane = tid & 63;
    int idx = blockIdx.x * 4 + (tid >> 6);
    if (idx >= ntot) return;
    bool user = idx < nu;
    int d = user ? idx : idx - nu;
    const int*    offp = user ? off_u : off_i;
    const float4* pay  = user ? pay_su : pay_si;
    const float*  Xown = user ? Xu : Xi;
    const __half* Xoth = user ? Xih : Xuh;
    int s = offp[d], e = offp[d + 1];
    if (s == e) { out[(size_t)idx * D + lane] = 0.f; return; }
    int g = lane >> 3;       // edge group 0..7
    int l = lane & 7;        // feature sub-lane: features 8l..8l+7
    float msum = 0.f, mcoef = 0.f;
    float acc[8] = {0.f, 0.f, 0.f, 0.f, 0.f, 0.f, 0.f, 0.f};
    for (int j = s + g; j < e; j += 8) {
        float4 p = pay[j];                         // broadcast within group
        float ex = __expf(p.x);
        float wown = user ? p.y : 1.f - p.y;
        msum += ex;
        mcoef += ex * wown;
        float cv = ex * (1.f - wown);
        int o2 = __float_as_int(p.z);
        const __half2* row = (const __half2*)(Xoth + (size_t)o2 * D + 8 * l);
        float2 f0 = __half22float2(row[0]);
        float2 f1 = __half22float2(row[1]);
        float2 f2 = __half22float2(row[2]);
        float2 f3 = __half22float2(row[3]);
        acc[0] += cv * f0.x; acc[1] += cv * f0.y;
        acc[2] += cv * f1.x; acc[3] += cv * f1.y;
        acc[4] += cv * f2.x; acc[5] += cv * f2.y;
        acc[6] += cv * f3.x; acc[7] += cv * f3.y;
    }
#pragma unroll
    for (int o = 32; o >= 8; o >>= 1) {
        msum  += __shfl_xor(msum, o, 64);
        mcoef += __shfl_xor(mcoef, o, 64);
#pragma unroll
        for (int q = 0; q < 8; ++q) acc[q] += __shfl_xor(acc[q], o, 64);
    }
    if (g == 0) {
        float inv = 1.f / msum;
        const float4* xo = (const float4*)(Xown + (size_t)d * D + 8 * l);
        float4 x0 = xo[0], x1 = xo[1];
        float4 r0, r1;
        r0.x = (mcoef * x0.x + acc[0]) * inv;
        r0.y = (mcoef * x0.y + acc[1]) * inv;
        r0.z = (mcoef * x0.z + acc[2]) * inv;
        r0.w = (mcoef * x0.w + acc[3]) * inv;
        r1.x = (mcoef * x1.x + acc[4]) * inv;
        r1.y = (mcoef * x1.y + acc[5]) * inv;
        r1.z = (mcoef * x1.z + acc[6]) * inv;
        r1.w = (mcoef * x1.w + acc[7]) * inv;
        float4* op = (float4*)(out + (size_t)idx * D + 8 * l);
        op[0] = r0;
        op[1] = r1;
    }
}

extern "C" void kernel_launch(void* const* d_in, const int* in_sizes, int n_in,
                              void* d_out, int out_size, void* d_ws, size_t ws_size,
                              hipStream_t stream) {
    const float* Xu        = (const float*)d_in[0];
    const float* Xi        = (const float*)d_in[1];
    const float* Wsrc      = (const float*)d_in[2];
    const float* bsrc      = (const float*)d_in[3];
    const float* Wdst      = (const float*)d_in[4];
    const float* bdst      = (const float*)d_in[5];
    const float* watt_rep  = (const float*)d_in[6];
    const float* batt_rep  = (const float*)d_in[7];  (void)batt_rep; // cancels in sigmoid
    const float* Wo        = (const float*)d_in[8];
    const float* bo        = (const float*)d_in[9];
    const float* Wu        = (const float*)d_in[10];
    const float* bu        = (const float*)d_in[11];
    const float* watt_agg  = (const float*)d_in[12];
    const float* batt_agg  = (const float*)d_in[13];
    const float* pref_user = (const float*)d_in[14];
    const float* pref_item = (const float*)d_in[15];
    const int* r_user      = (const int*)d_in[16];
    const int* r_item      = (const int*)d_in[17];

    int nu = in_sizes[0] / D;
    int ni = in_sizes[1] / D;
    int R  = in_sizes[16];

    float* ws = (float*)d_ws;
    size_t off = 0;
    __half* packU = (__half*)(ws + off); off += (size_t)nu * D * 2;   // SoA
    __half* packI = (__half*)(ws + off); off += (size_t)ni * D * 2;
    __half* Xuh = (__half*)(ws + off); off += (size_t)nu * D / 2;
    __half* Xih = (__half*)(ws + off); off += (size_t)ni * D / 2;
    float4* pay_su = (float4*)(ws + off); off += (size_t)R * 4;
    float4* pay_si = (float4*)(ws + off); off += (size_t)R * 4;
    int2* edges = (int2*)(ws + off); off += (size_t)R * 2;
    int* cnt_u = (int*)(ws + off); off += (size_t)nu;         // doubles as cursor
    int* cnt_i = (int*)(ws + off); off += (size_t)ni;
    int* bsum  = (int*)(ws + off); off += 256;
    int* off_u = (int*)(ws + off); off += (size_t)nu + 1;
    int* off_i = (int*)(ws + off); off += (size_t)ni + 1;

    // zero counters (custom kernel; rocclr fillBuffer ~7 GB/s for small fills,
    // cooperative grid.sync ~50us/sync, lookback spin ~10us — all measured worse)
    int n4 = (nu + ni + 3) / 4;
    k_init<<<128, 256, 0, stream>>>((int4*)cnt_u, n4);

    // edge counts (depends only on indices)
    k_count<<<(R + 255) / 256, 256, 0, stream>>>(r_user, r_item, cnt_u, cnt_i, R);

    // two-level scan (assumes <=64 scan-blocks per side: n <= 65536)
    int Bu = (nu + EPB - 1) / EPB, Bi = (ni + EPB - 1) / EPB;
    k_scan_local<<<Bu + Bi, 256, 0, stream>>>(
        cnt_u, off_u, nu, cnt_i, off_i, ni, bsum, Bu);
    k_scan_add<<<Bu + Bi, 256, 0, stream>>>(
        off_u, cnt_u, nu, off_i, cnt_i, ni, bsum, Bu, Bi);

    // user-CSR edge list
    k_fill_u<<<(R + 255) / 256, 256, 0, stream>>>(r_user, r_item, cnt_u, edges, R);

    // node-level precompute via MFMA (LDS-staged X/P tile), both domains
    int ntu = (nu + 15) / 16, nti = (ni + 15) / 16;
    k_nodes_mfma<<<1024, 256, 0, stream>>>(
        Xu, pref_user, nu, ntu, Xi, pref_item, ni, nti,
        Wsrc, bsrc, Wdst, bdst, Wo, bo, Wu, bu,
        packU, Xuh, packI, Xih);

    // per-review attention in user-CSR order (8 reviews/wave, SoA loads)
    k_rev1<<<(R + 31) / 32, 256, 0, stream>>>(
        edges, packU, packI,
        (const float4*)watt_rep, (const float4*)watt_agg, batt_agg,
        cnt_i, pay_su, pay_si, R);

    // per-destination softmax + weighted sum (no max pass; 8 edges in flight)
    int ntot = nu + ni;
    k_agg<<<(ntot + 3) / 4, 256, 0, stream>>>(
        off_u, off_i, pay_su, pay_si,
        Xu, Xi, Xuh, Xih, (float*)d_out, nu, ntot);
}